// Round 4
// baseline (18.032 us; speedup 1.0000x reference)
//
#include <hip/hip_runtime.h>

// ContrastiveLoss collapses to:
//   v = sum_i mask_i * latent_i / max(||latent_i||, eps)   (64-vector)
//   out = COF1 * (||v||^2 - sum(mask)) / (2N)
// O(N*d), ~2 MB traffic -> launch/latency bound. Single fused dispatch:
// 256 blocks write 65-float partials + release-store a MAGIC flag;
// block 0 spin-waits all flags (poison-tolerant handshake), acquire-fences,
// reduces, writes the scalar, and resets flags for the next graph replay.

#define EPSV 1e-8f
#define COF1 0.01f

constexpr int N_ROWS = 8192;
constexpr int DIM = 64;
constexpr int TPB = 256;
constexpr int WPB = TPB / 64;                    // 4 waves/block
constexpr int BLOCKS = 256;                      // 1 block/CU
constexpr int RPW = N_ROWS / (BLOCKS * WPB);     // 8 rows/wave
constexpr int SLOT = 68;                         // v[64] + cnt + pad (16B align)
constexpr unsigned MAGIC = 0x5EEDF00Du;

__global__ __launch_bounds__(TPB, 2) void cl_fused(const float* __restrict__ latent,
                                                   float* __restrict__ ws,
                                                   unsigned* __restrict__ flags,
                                                   float* __restrict__ out) {
    const int wv   = threadIdx.x >> 6;
    const int lane = threadIdx.x & 63;
    const int g    = lane >> 4;      // row within 4-row batch
    const int c4   = lane & 15;      // column quad (cols 4*c4..4*c4+3)
    const int row0 = (blockIdx.x * WPB + wv) * RPW;

    const float4* lat4 = (const float4*)latent;

    // ---- phase 1: per-wave partial v + count (float4 loads, 16-lane rows) ----
    float4 v = make_float4(0.f, 0.f, 0.f, 0.f);
    float cnt = 0.0f;

    #pragma unroll
    for (int b = 0; b < RPW / 4; ++b) {
        const int row = row0 + b * 4 + g;
        float4 x = lat4[row * (DIM / 4) + c4];
        float s = x.x + x.y + x.z + x.w;
        float q = x.x * x.x + x.y * x.y + x.z * x.z + x.w * x.w;
        #pragma unroll
        for (int off = 8; off; off >>= 1) {       // reduce within 16-lane group
            s += __shfl_xor(s, off);
            q += __shfl_xor(q, off);
        }
        if (s != 0.0f) {
            float inv = 1.0f / fmaxf(sqrtf(q), EPSV);
            v.x += x.x * inv; v.y += x.y * inv;
            v.z += x.z * inv; v.w += x.w * inv;
            if (c4 == 0) cnt += 1.0f;             // one count per row
        }
    }
    #pragma unroll
    for (int off = 16; off <= 32; off <<= 1) {    // combine the 4 row-groups
        v.x += __shfl_xor(v.x, off); v.y += __shfl_xor(v.y, off);
        v.z += __shfl_xor(v.z, off); v.w += __shfl_xor(v.w, off);
        cnt += __shfl_xor(cnt, off);
    }

    __shared__ float4 sv4[WPB][16];
    __shared__ float  scnt[WPB];
    if (lane < 16) sv4[wv][c4] = v;
    if (lane == 0) scnt[wv] = cnt;
    __syncthreads();

    // ---- publish block partial ----
    if (wv == 0 && lane < 16) {
        float4 a = sv4[0][c4];
        float4 b1 = sv4[1][c4], b2 = sv4[2][c4], b3 = sv4[3][c4];
        a.x += b1.x + b2.x + b3.x; a.y += b1.y + b2.y + b3.y;
        a.z += b1.z + b2.z + b3.z; a.w += b1.w + b2.w + b3.w;
        ((float4*)(ws + blockIdx.x * SLOT))[c4] = a;
        if (lane == 0)
            ws[blockIdx.x * SLOT + 64] = scnt[0] + scnt[1] + scnt[2] + scnt[3];
        __threadfence();                          // writers fence their stores
    }
    __syncthreads();
    if (threadIdx.x == 0)
        __hip_atomic_store(&flags[blockIdx.x], MAGIC,
                           __ATOMIC_RELEASE, __HIP_MEMORY_SCOPE_AGENT);

    if (blockIdx.x != 0) return;

    // ---- block 0: wait for all 256 partials (thread t polls flag t) ----
    while (__hip_atomic_load(&flags[threadIdx.x],
                             __ATOMIC_ACQUIRE, __HIP_MEMORY_SCOPE_AGENT) != MAGIC) {}
    __syncthreads();
    __threadfence();                              // invalidate stale cached lines

    // ---- final reduction: wave wv covers slots wv*64 .. wv*64+63 ----
    const float* base = ws + (wv * 64) * SLOT;
    float acc = 0.0f, c = 0.0f;
    for (int b0 = 0; b0 < 64; b0 += 8) {
        float t[8], tc[8];
        #pragma unroll
        for (int j = 0; j < 8; ++j) {             // 16 independent loads in flight
            t[j]  = base[(b0 + j) * SLOT + lane];
            tc[j] = base[(b0 + j) * SLOT + 64];
        }
        #pragma unroll
        for (int j = 0; j < 8; ++j) { acc += t[j]; c += tc[j]; }
    }

    __shared__ float fv[WPB][64];
    __shared__ float fc[WPB];
    fv[wv][lane] = acc;
    if (lane == 0) fc[wv] = c;
    __syncthreads();

    if (wv == 0) {
        float a = fv[0][lane] + fv[1][lane] + fv[2][lane] + fv[3][lane];
        float d = a * a;
        #pragma unroll
        for (int off = 32; off; off >>= 1)
            d += __shfl_xor(d, off);
        if (lane == 0) {
            float ctot = fc[0] + fc[1] + fc[2] + fc[3];
            out[0] = COF1 * (d - ctot) / (2.0f * (float)N_ROWS);
        }
    }
    __syncthreads();
    flags[threadIdx.x] = 0;   // reset handshake for the next replay
}

extern "C" void kernel_launch(void* const* d_in, const int* in_sizes, int n_in,
                              void* d_out, int out_size, void* d_ws, size_t ws_size,
                              hipStream_t stream) {
    const float* latent = (const float*)d_in[0];
    float* out = (float*)d_out;
    float* ws = (float*)d_ws;                       // 256*68*4 = 69,632 B partials
    unsigned* flags = (unsigned*)(ws + BLOCKS * SLOT);  // + 1 KB flags

    cl_fused<<<BLOCKS, TPB, 0, stream>>>(latent, ws, flags, out);
}

// Round 5
// 11.719 us; speedup vs baseline: 1.5386x; 1.5386x over previous
//
#include <hip/hip_runtime.h>

// ContrastiveLoss collapses to:
//   v = sum_i mask_i * latent_i / max(||latent_i||, eps)   (64-vector)
//   out = COF1 * (||v||^2 - sum(mask)) / (2N)
// O(N*d), ~2 MB traffic -> launch/latency bound. Two dispatches beat any
// in-kernel grid handshake on this chip (round-4 lesson: device-scope
// flag spin cost ~+5us vs ~2-3us for a 2nd graph dispatch).

#define EPSV 1e-8f
#define COF1 0.01f

constexpr int N_ROWS = 8192;
constexpr int DIM = 64;
constexpr int TPB = 256;
constexpr int WPB = TPB / 64;                     // 4 waves/block
constexpr int BLOCKS = 128;                       // 512 waves
constexpr int RPW = N_ROWS / (BLOCKS * WPB);      // 16 rows/wave -> 4 float4 batches
constexpr int SLOT = 68;                          // v[64] + cnt + pad (16B align)

// Kernel 1: lane L -> row-group g=L>>4, column quad c4=L&15. All 4 batches'
// float4 loads issued up-front (one HBM round trip); 4 independent shuffle
// chains overlap. Block combines 4 waves in LDS -> one 68-float slot.
__global__ __launch_bounds__(TPB, 2) void cl_partial(const float* __restrict__ latent,
                                                     float* __restrict__ ws) {
    const int wv   = threadIdx.x >> 6;
    const int lane = threadIdx.x & 63;
    const int g    = lane >> 4;
    const int c4   = lane & 15;
    const int row0 = (blockIdx.x * WPB + wv) * RPW;

    const float4* lat4 = (const float4*)latent;

    float4 x[RPW / 4];
    #pragma unroll
    for (int b = 0; b < RPW / 4; ++b)
        x[b] = lat4[(row0 + b * 4 + g) * (DIM / 4) + c4];

    float4 v = make_float4(0.f, 0.f, 0.f, 0.f);
    float cnt = 0.0f;
    #pragma unroll
    for (int b = 0; b < RPW / 4; ++b) {
        float s = x[b].x + x[b].y + x[b].z + x[b].w;
        float q = x[b].x * x[b].x + x[b].y * x[b].y + x[b].z * x[b].z + x[b].w * x[b].w;
        #pragma unroll
        for (int off = 8; off; off >>= 1) {       // reduce within 16-lane row group
            s += __shfl_xor(s, off);
            q += __shfl_xor(q, off);
        }
        if (s != 0.0f) {
            float inv = 1.0f / fmaxf(sqrtf(q), EPSV);
            v.x += x[b].x * inv; v.y += x[b].y * inv;
            v.z += x[b].z * inv; v.w += x[b].w * inv;
            if (c4 == 0) cnt += 1.0f;             // one count per row
        }
    }
    #pragma unroll
    for (int off = 16; off <= 32; off <<= 1) {    // combine the 4 row-groups
        v.x += __shfl_xor(v.x, off); v.y += __shfl_xor(v.y, off);
        v.z += __shfl_xor(v.z, off); v.w += __shfl_xor(v.w, off);
        cnt += __shfl_xor(cnt, off);
    }

    __shared__ float4 sv4[WPB][16];
    __shared__ float  scnt[WPB];
    if (lane < 16) sv4[wv][c4] = v;
    if (lane == 0) scnt[wv] = cnt;
    __syncthreads();

    if (wv == 0 && lane < 16) {
        float4 a = sv4[0][c4];
        float4 b1 = sv4[1][c4], b2 = sv4[2][c4], b3 = sv4[3][c4];
        a.x += b1.x + b2.x + b3.x; a.y += b1.y + b2.y + b3.y;
        a.z += b1.z + b2.z + b3.z; a.w += b1.w + b2.w + b3.w;
        ((float4*)(ws + blockIdx.x * SLOT))[c4] = a;
        if (lane == 0)
            ws[blockIdx.x * SLOT + 64] = scnt[0] + scnt[1] + scnt[2] + scnt[3];
    }
}

// Kernel 2: 128 slots; wave wv covers slots wv*32..wv*32+31 as two fully
// unrolled 16-deep load batches (all loads in flight), then LDS combine.
__global__ __launch_bounds__(256) void cl_final(const float* __restrict__ ws,
                                                float* __restrict__ out) {
    const int wv   = threadIdx.x >> 6;
    const int lane = threadIdx.x & 63;

    const float* base = ws + (wv * 32) * SLOT;
    float acc = 0.0f, c = 0.0f;
    #pragma unroll
    for (int h = 0; h < 2; ++h) {
        float t[16], tc[16];
        #pragma unroll
        for (int j = 0; j < 16; ++j) {            // 32 independent loads in flight
            t[j]  = base[(h * 16 + j) * SLOT + lane];
            tc[j] = base[(h * 16 + j) * SLOT + 64];
        }
        #pragma unroll
        for (int j = 0; j < 16; ++j) { acc += t[j]; c += tc[j]; }
    }

    __shared__ float fv[WPB][64];
    __shared__ float fc[WPB];
    fv[wv][lane] = acc;
    if (lane == 0) fc[wv] = c;
    __syncthreads();

    if (wv == 0) {
        float a = fv[0][lane] + fv[1][lane] + fv[2][lane] + fv[3][lane];
        float d = a * a;
        #pragma unroll
        for (int off = 32; off; off >>= 1)
            d += __shfl_xor(d, off);
        if (lane == 0) {
            float ctot = fc[0] + fc[1] + fc[2] + fc[3];
            out[0] = COF1 * (d - ctot) / (2.0f * (float)N_ROWS);
        }
    }
}

extern "C" void kernel_launch(void* const* d_in, const int* in_sizes, int n_in,
                              void* d_out, int out_size, void* d_ws, size_t ws_size,
                              hipStream_t stream) {
    const float* latent = (const float*)d_in[0];
    float* out = (float*)d_out;
    float* ws = (float*)d_ws;   // 128*68*4 = 34,816 bytes

    cl_partial<<<BLOCKS, TPB, 0, stream>>>(latent, ws);
    cl_final<<<1, 256, 0, stream>>>(ws, out);
}